// Round 1
// baseline (819.228 us; speedup 1.0000x reference)
//
#include <hip/hip_runtime.h>
#include <hip/hip_bf16.h>

#define N_NODES  50000
#define HID      64
#define N_CLS    8
#define N_GRAPHS 500

// ---------------- degree ----------------
__global__ void k_deg(const int* __restrict__ col, int E, float* __restrict__ deg) {
    int i = blockIdx.x * blockDim.x + threadIdx.x;
    if (i < E) atomicAdd(&deg[col[i]], 1.0f);
}

__global__ void k_dinv(float* __restrict__ deg, int N) {
    int i = blockIdx.x * blockDim.x + threadIdx.x;
    if (i < N) deg[i] = rsqrtf(deg[i] + 1.0f);   // +1 = self loop
}

// ---------------- GEMM [N,64] @ [64,64] ----------------
__global__ __launch_bounds__(256) void k_gemm64(const float* __restrict__ H,
                                                const float* __restrict__ W,
                                                float* __restrict__ O, int N) {
    __shared__ float Ws[64 * 64];
    int tid = threadIdx.x;
    #pragma unroll
    for (int i = tid; i < 64 * 64; i += 256) Ws[i] = W[i];
    __syncthreads();
    int r = blockIdx.x * 4 + (tid >> 6);
    int c = tid & 63;
    if (r >= N) return;
    const float* hr = H + (size_t)r * HID;
    float acc = 0.f;
    #pragma unroll
    for (int k = 0; k < HID; ++k) acc += hr[k] * Ws[k * 64 + c];
    O[(size_t)r * HID + c] = acc;
}

// ---------------- agg init with self loop: agg = xw * dinv^2 ----------------
__global__ void k_selfinit(const float* __restrict__ xw, const float* __restrict__ dinv,
                           float* __restrict__ agg, int N) {
    int i = blockIdx.x * blockDim.x + threadIdx.x;
    if (i < N * HID) {
        int r = i >> 6;
        float d = dinv[r];
        agg[i] = xw[i] * d * d;
    }
}

// ---------------- edge scatter: agg[col] += xw[row] * dinv[row]*dinv[col] ----------------
__global__ void k_edges(const int* __restrict__ row, const int* __restrict__ col,
                        const float* __restrict__ dinv, const float* __restrict__ xw,
                        float* __restrict__ agg, int E) {
    long long gid = (long long)blockIdx.x * blockDim.x + threadIdx.x;
    int e = (int)(gid >> 6);
    int f = (int)(gid & 63);
    if (e >= E) return;
    int r = row[e], c = col[e];
    float nrm = dinv[r] * dinv[c];
    atomicAdd(&agg[(size_t)c * HID + f], xw[(size_t)r * HID + f] * nrm);
}

// ---------------- bias + optional relu ----------------
__global__ void k_bias_act(float* __restrict__ agg, const float* __restrict__ b,
                           int N, int do_relu) {
    int i = blockIdx.x * blockDim.x + threadIdx.x;
    if (i < N * HID) {
        float v = agg[i] + b[i & 63];
        agg[i] = do_relu ? fmaxf(v, 0.0f) : v;
    }
}

// ---------------- mean pool (accumulate) ----------------
__global__ void k_pool(const float* __restrict__ h, const int* __restrict__ batch,
                       float* __restrict__ sums, float* __restrict__ cnts, int N) {
    long long gid = (long long)blockIdx.x * blockDim.x + threadIdx.x;
    int i = (int)(gid >> 6);
    int f = (int)(gid & 63);
    if (i >= N) return;
    int g = batch[i];
    atomicAdd(&sums[(size_t)g * HID + f], h[(size_t)i * HID + f]);
    if (f == 0) atomicAdd(&cnts[g], 1.0f);
}

// ---------------- final linear: out[g,c] = (sums[g]/cnt[g]) @ Wl + bl ----------------
__global__ void k_final(const float* __restrict__ sums, const float* __restrict__ cnts,
                        const float* __restrict__ Wl, const float* __restrict__ bl,
                        float* __restrict__ out) {
    int gid = blockIdx.x * blockDim.x + threadIdx.x;
    if (gid >= N_GRAPHS * N_CLS) return;
    int g = gid >> 3, c = gid & 7;
    float inv = 1.0f / fmaxf(cnts[g], 1.0f);
    float acc = bl[c];
    #pragma unroll
    for (int f = 0; f < HID; ++f) acc += sums[(size_t)g * HID + f] * inv * Wl[f * N_CLS + c];
    out[gid] = acc;
}

extern "C" void kernel_launch(void* const* d_in, const int* in_sizes, int n_in,
                              void* d_out, int out_size, void* d_ws, size_t ws_size,
                              hipStream_t stream) {
    const float* x    = (const float*)d_in[0];
    const int*   ei   = (const int*)d_in[1];
    const int*   batch= (const int*)d_in[2];
    const float* W1   = (const float*)d_in[3];
    const float* b1   = (const float*)d_in[4];
    const float* W2   = (const float*)d_in[5];
    const float* b2   = (const float*)d_in[6];
    const float* W3   = (const float*)d_in[7];
    const float* b3   = (const float*)d_in[8];
    const float* Wl   = (const float*)d_in[9];
    const float* bl   = (const float*)d_in[10];
    float* out = (float*)d_out;

    const int N = in_sizes[0] / HID;       // 50000
    const int E = in_sizes[1] / 2;         // 800000
    const int* row = ei;                   // edge_index[0]
    const int* col = ei + E;               // edge_index[1]

    // workspace layout (floats)
    float* ws = (float*)d_ws;
    float* dinv = ws;                              // N
    float* cnts = ws + 50048;                      // 500
    float* sums = ws + 50560;                      // 500*64 = 32000
    float* bufA = ws + 82624;                      // N*64
    float* bufB = bufA + (size_t)N * HID;          // N*64
    float* bufC = bufB + (size_t)N * HID;          // N*64

    // zero-init deg and pools
    hipMemsetAsync(dinv, 0, (size_t)N * sizeof(float), stream);
    hipMemsetAsync(cnts, 0, 512 * sizeof(float), stream);
    hipMemsetAsync(sums, 0, (size_t)N_GRAPHS * HID * sizeof(float), stream);

    const int T = 256;
    // degrees -> dinv
    k_deg <<<(E + T - 1) / T, T, 0, stream>>>(col, E, dinv);
    k_dinv<<<(N + T - 1) / T, T, 0, stream>>>(dinv, N);

    long long nfeat = (long long)N * HID;
    int gFeat = (int)((nfeat + T - 1) / T);
    long long nedge = (long long)E * HID;
    int gEdge = (int)((nedge + T - 1) / T);
    int gGemm = (N + 3) / 4;

    // ---- layer 1: x -> bufA ----
    k_gemm64  <<<gGemm, T, 0, stream>>>(x, W1, bufB, N);
    k_selfinit<<<gFeat, T, 0, stream>>>(bufB, dinv, bufA, N);
    k_edges   <<<gEdge, T, 0, stream>>>(row, col, dinv, bufB, bufA, E);
    k_bias_act<<<gFeat, T, 0, stream>>>(bufA, b1, N, 1);

    // ---- layer 2: bufA -> bufC ----
    k_gemm64  <<<gGemm, T, 0, stream>>>(bufA, W2, bufB, N);
    k_selfinit<<<gFeat, T, 0, stream>>>(bufB, dinv, bufC, N);
    k_edges   <<<gEdge, T, 0, stream>>>(row, col, dinv, bufB, bufC, E);
    k_bias_act<<<gFeat, T, 0, stream>>>(bufC, b2, N, 1);

    // ---- layer 3: bufC -> bufA ----
    k_gemm64  <<<gGemm, T, 0, stream>>>(bufC, W3, bufB, N);
    k_selfinit<<<gFeat, T, 0, stream>>>(bufB, dinv, bufA, N);
    k_edges   <<<gEdge, T, 0, stream>>>(row, col, dinv, bufB, bufA, E);
    k_bias_act<<<gFeat, T, 0, stream>>>(bufA, b3, N, 0);

    // ---- pool + final linear ----
    k_pool <<<gFeat, T, 0, stream>>>(bufA, batch, sums, cnts, N);
    k_final<<<(N_GRAPHS * N_CLS + T - 1) / T, T, 0, stream>>>(sums, cnts, Wl, bl, out);
}

// Round 2
// 362.562 us; speedup vs baseline: 2.2596x; 2.2596x over previous
//
#include <hip/hip_runtime.h>
#include <hip/hip_bf16.h>

#define HID      64
#define N_CLS    8
#define N_GRAPHS 500

// ---------------- CSR build: histogram of targets ----------------
__global__ void k_hist(const int* __restrict__ col, int E, int* __restrict__ cnt) {
    int e = blockIdx.x * blockDim.x + threadIdx.x;
    if (e < E) atomicAdd(&cnt[col[e]], 1);
}

// dinv[i] = rsqrt(cnt[i] + 1)   (+1 self loop)
__global__ void k_dinv(const int* __restrict__ cnt, float* __restrict__ dinv, int N) {
    int i = blockIdx.x * blockDim.x + threadIdx.x;
    if (i < N) dinv[i] = rsqrtf((float)cnt[i] + 1.0f);
}

// ---------------- 3-kernel exclusive scan over cnt[N] ----------------
__global__ void k_scan1(const int* __restrict__ cnt, int* __restrict__ partial, int N) {
    __shared__ int sdata[256];
    int i = blockIdx.x * 256 + threadIdx.x;
    sdata[threadIdx.x] = (i < N) ? cnt[i] : 0;
    __syncthreads();
    for (int s = 128; s > 0; s >>= 1) {
        if (threadIdx.x < s) sdata[threadIdx.x] += sdata[threadIdx.x + s];
        __syncthreads();
    }
    if (threadIdx.x == 0) partial[blockIdx.x] = sdata[0];
}

__global__ void k_scan2(int* __restrict__ partial, int nblk) {   // single block, nblk<=256
    __shared__ int sdata[256];
    int t = threadIdx.x;
    int orig = (t < nblk) ? partial[t] : 0;
    sdata[t] = orig;
    __syncthreads();
    for (int off = 1; off < 256; off <<= 1) {
        int v = (t >= off) ? sdata[t - off] : 0;
        __syncthreads();
        sdata[t] += v;
        __syncthreads();
    }
    if (t < nblk) partial[t] = sdata[t] - orig;   // exclusive
}

__global__ void k_scan3(const int* __restrict__ cnt, const int* __restrict__ partial,
                        int* __restrict__ start, int N) {
    __shared__ int sdata[256];
    int i = blockIdx.x * 256 + threadIdx.x;
    int orig = (i < N) ? cnt[i] : 0;
    sdata[threadIdx.x] = orig;
    __syncthreads();
    for (int off = 1; off < 256; off <<= 1) {
        int v = (threadIdx.x >= off) ? sdata[threadIdx.x - off] : 0;
        __syncthreads();
        sdata[threadIdx.x] += v;
        __syncthreads();
    }
    if (i < N) start[i] = sdata[threadIdx.x] - orig + partial[blockIdx.x];
}

// ---------------- place edges into CSR ----------------
__global__ void k_place(const int* __restrict__ row, const int* __restrict__ col,
                        const int* __restrict__ start, int* __restrict__ cursor,
                        int* __restrict__ adj, int E) {
    int e = blockIdx.x * blockDim.x + threadIdx.x;
    if (e < E) {
        int c = col[e];
        int p = atomicAdd(&cursor[c], 1);
        adj[start[c] + p] = row[e];
    }
}

// ---------------- GEMM [N,64]@[64,64], epilogue *dinv[row] ----------------
__global__ __launch_bounds__(256) void k_gemm64(const float* __restrict__ H,
                                                const float* __restrict__ W,
                                                const float* __restrict__ dinv,
                                                float* __restrict__ O, int N) {
    __shared__ float Ws[64 * 64];
    __shared__ float Hs[16 * 64];
    int tid = threadIdx.x;
    #pragma unroll
    for (int i = tid; i < 64 * 64; i += 256) Ws[i] = W[i];
    int rbase = blockIdx.x * 16;
    #pragma unroll
    for (int i = tid; i < 16 * 64; i += 256) {
        int r = rbase + (i >> 6);
        Hs[i] = (r < N) ? H[(size_t)r * HID + (i & 63)] : 0.0f;
    }
    __syncthreads();
    int c = tid & 63;
    int lr = (tid >> 6) * 4;           // local row 0,4,8,12
    float a0 = 0, a1 = 0, a2 = 0, a3 = 0;
    const float* h = Hs + lr * 64;
    #pragma unroll
    for (int k = 0; k < 64; ++k) {
        float w = Ws[k * 64 + c];
        a0 += h[k] * w;
        a1 += h[64 + k] * w;
        a2 += h[128 + k] * w;
        a3 += h[192 + k] * w;
    }
    int r = rbase + lr;
    if (r + 3 < N) {
        float* o = O + (size_t)r * HID;
        o[c]       = a0 * dinv[r];
        o[64 + c]  = a1 * dinv[r + 1];
        o[128 + c] = a2 * dinv[r + 2];
        o[192 + c] = a3 * dinv[r + 3];
    } else {
        if (r < N)     O[(size_t)r * HID + c]       = a0 * dinv[r];
        if (r + 1 < N) O[(size_t)(r + 1) * HID + c] = a1 * dinv[r + 1];
        if (r + 2 < N) O[(size_t)(r + 2) * HID + c] = a2 * dinv[r + 2];
        if (r + 3 < N) O[(size_t)(r + 3) * HID + c] = a3 * dinv[r + 3];
    }
}

// ---------------- gather-aggregate per node (one wave per node) ----------------
// out[c] = act( dinv[c] * (xws[c] + sum_{e into c} xws[adj[e]]) + b )
__global__ __launch_bounds__(256) void k_gather(const int* __restrict__ adj,
                                                const int* __restrict__ start,
                                                const int* __restrict__ cnt,
                                                const float* __restrict__ dinv,
                                                const float* __restrict__ xws,
                                                const float* __restrict__ b,
                                                float* __restrict__ out,
                                                int N, int do_relu) {
    int node = blockIdx.x * 4 + (threadIdx.x >> 6);
    int f = threadIdx.x & 63;
    if (node >= N) return;
    int s = start[node];
    int n = cnt[node];
    float acc = xws[(size_t)node * HID + f];      // self loop
    int i = 0;
    for (; i + 4 <= n; i += 4) {
        int r0 = adj[s + i], r1 = adj[s + i + 1], r2 = adj[s + i + 2], r3 = adj[s + i + 3];
        float v0 = xws[(size_t)r0 * HID + f];
        float v1 = xws[(size_t)r1 * HID + f];
        float v2 = xws[(size_t)r2 * HID + f];
        float v3 = xws[(size_t)r3 * HID + f];
        acc += v0 + v1 + v2 + v3;
    }
    for (; i < n; ++i) acc += xws[(size_t)adj[s + i] * HID + f];
    float v = acc * dinv[node] + b[f];
    out[(size_t)node * HID + f] = do_relu ? fmaxf(v, 0.0f) : v;
}

// ---------------- mean pool (accumulate) ----------------
__global__ void k_pool(const float* __restrict__ h, const int* __restrict__ batch,
                       float* __restrict__ sums, float* __restrict__ cnts, int N) {
    long long gid = (long long)blockIdx.x * blockDim.x + threadIdx.x;
    int i = (int)(gid >> 6);
    int f = (int)(gid & 63);
    if (i >= N) return;
    int g = batch[i];
    atomicAdd(&sums[(size_t)g * HID + f], h[(size_t)i * HID + f]);
    if (f == 0) atomicAdd(&cnts[g], 1.0f);
}

// ---------------- final linear ----------------
__global__ void k_final(const float* __restrict__ sums, const float* __restrict__ cnts,
                        const float* __restrict__ Wl, const float* __restrict__ bl,
                        float* __restrict__ out) {
    int gid = blockIdx.x * blockDim.x + threadIdx.x;
    if (gid >= N_GRAPHS * N_CLS) return;
    int g = gid >> 3, c = gid & 7;
    float inv = 1.0f / fmaxf(cnts[g], 1.0f);
    float acc = bl[c];
    #pragma unroll
    for (int f = 0; f < HID; ++f) acc += sums[(size_t)g * HID + f] * inv * Wl[f * N_CLS + c];
    out[gid] = acc;
}

extern "C" void kernel_launch(void* const* d_in, const int* in_sizes, int n_in,
                              void* d_out, int out_size, void* d_ws, size_t ws_size,
                              hipStream_t stream) {
    const float* x     = (const float*)d_in[0];
    const int*   ei    = (const int*)d_in[1];
    const int*   batch = (const int*)d_in[2];
    const float* W1    = (const float*)d_in[3];
    const float* b1    = (const float*)d_in[4];
    const float* W2    = (const float*)d_in[5];
    const float* b2    = (const float*)d_in[6];
    const float* W3    = (const float*)d_in[7];
    const float* b3    = (const float*)d_in[8];
    const float* Wl    = (const float*)d_in[9];
    const float* bl    = (const float*)d_in[10];
    float* out = (float*)d_out;

    const int N = in_sizes[0] / HID;   // 50000
    const int E = in_sizes[1] / 2;     // 800000
    const int* row = ei;
    const int* col = ei + E;

    // ---- workspace layout (4-byte units) ----
    char* wsb = (char*)d_ws;
    int*   cnt     = (int*)wsb;                         // N       @ 0
    int*   start   = cnt + 50048;                       // N
    int*   cursor  = start + 50048;                     // N
    int*   partial = cursor + 50048;                    // 256
    float* dinv    = (float*)(partial + 256);           // N
    float* pcnts   = dinv + 50048;                      // 512
    float* psums   = pcnts + 512;                       // 500*64
    int*   adj     = (int*)(psums + 32000);             // E
    float* bufA    = (float*)(adj + 800000);            // N*64
    float* bufB    = bufA + (size_t)N * HID;            // N*64

    const int T = 256;
    const int nblk = (N + 255) / 256;                   // 196

    // zero: cnt, cursor, pool accumulators
    hipMemsetAsync(cnt, 0, (size_t)N * sizeof(int), stream);
    hipMemsetAsync(cursor, 0, (size_t)N * sizeof(int), stream);
    hipMemsetAsync(pcnts, 0, 512 * sizeof(float), stream);
    hipMemsetAsync(psums, 0, (size_t)N_GRAPHS * HID * sizeof(float), stream);

    // ---- CSR build + dinv ----
    k_hist <<<(E + T - 1) / T, T, 0, stream>>>(col, E, cnt);
    k_dinv <<<nblk, T, 0, stream>>>(cnt, dinv, N);
    k_scan1<<<nblk, T, 0, stream>>>(cnt, partial, N);
    k_scan2<<<1, T, 0, stream>>>(partial, nblk);
    k_scan3<<<nblk, T, 0, stream>>>(cnt, partial, start, N);
    k_place<<<(E + T - 1) / T, T, 0, stream>>>(row, col, start, cursor, adj, E);

    int gGemm = (N + 15) / 16;          // 3125
    int gGath = (N + 3) / 4;            // 12500

    // ---- layer 1 ----
    k_gemm64<<<gGemm, T, 0, stream>>>(x, W1, dinv, bufA, N);
    k_gather<<<gGath, T, 0, stream>>>(adj, start, cnt, dinv, bufA, b1, bufB, N, 1);
    // ---- layer 2 ----
    k_gemm64<<<gGemm, T, 0, stream>>>(bufB, W2, dinv, bufA, N);
    k_gather<<<gGath, T, 0, stream>>>(adj, start, cnt, dinv, bufA, b2, bufB, N, 1);
    // ---- layer 3 ----
    k_gemm64<<<gGemm, T, 0, stream>>>(bufB, W3, dinv, bufA, N);
    k_gather<<<gGath, T, 0, stream>>>(adj, start, cnt, dinv, bufA, b3, bufB, N, 0);

    // ---- pool + head ----
    k_pool <<<(int)(((long long)N * HID + T - 1) / T), T, 0, stream>>>(bufB, batch, psums, pcnts, N);
    k_final<<<(N_GRAPHS * N_CLS + T - 1) / T, T, 0, stream>>>(psums, pcnts, Wl, bl, out);
}

// Round 3
// 323.819 us; speedup vs baseline: 2.5299x; 1.1196x over previous
//
#include <hip/hip_runtime.h>
#include <hip/hip_bf16.h>

#define HID      64
#define N_CLS    8
#define N_GRAPHS 500

// ---------------- CSR build: histogram of targets ----------------
__global__ void k_hist(const int* __restrict__ col, int E, int* __restrict__ cnt) {
    int e = blockIdx.x * blockDim.x + threadIdx.x;
    if (e < E) atomicAdd(&cnt[col[e]], 1);
}

// dinv[i] = rsqrt(cnt[i] + 1)   (+1 self loop)
__global__ void k_dinv(const int* __restrict__ cnt, float* __restrict__ dinv, int N) {
    int i = blockIdx.x * blockDim.x + threadIdx.x;
    if (i < N) dinv[i] = rsqrtf((float)cnt[i] + 1.0f);
}

// ---------------- 3-kernel exclusive scan over cnt[N] ----------------
__global__ void k_scan1(const int* __restrict__ cnt, int* __restrict__ partial, int N) {
    __shared__ int sdata[256];
    int i = blockIdx.x * 256 + threadIdx.x;
    sdata[threadIdx.x] = (i < N) ? cnt[i] : 0;
    __syncthreads();
    for (int s = 128; s > 0; s >>= 1) {
        if (threadIdx.x < s) sdata[threadIdx.x] += sdata[threadIdx.x + s];
        __syncthreads();
    }
    if (threadIdx.x == 0) partial[blockIdx.x] = sdata[0];
}

__global__ void k_scan2(int* __restrict__ partial, int nblk) {   // single block, nblk<=256
    __shared__ int sdata[256];
    int t = threadIdx.x;
    int orig = (t < nblk) ? partial[t] : 0;
    sdata[t] = orig;
    __syncthreads();
    for (int off = 1; off < 256; off <<= 1) {
        int v = (t >= off) ? sdata[t - off] : 0;
        __syncthreads();
        sdata[t] += v;
        __syncthreads();
    }
    if (t < nblk) partial[t] = sdata[t] - orig;   // exclusive
}

__global__ void k_scan3(const int* __restrict__ cnt, const int* __restrict__ partial,
                        int* __restrict__ start, int N) {
    __shared__ int sdata[256];
    int i = blockIdx.x * 256 + threadIdx.x;
    int orig = (i < N) ? cnt[i] : 0;
    sdata[threadIdx.x] = orig;
    __syncthreads();
    for (int off = 1; off < 256; off <<= 1) {
        int v = (threadIdx.x >= off) ? sdata[threadIdx.x - off] : 0;
        __syncthreads();
        sdata[threadIdx.x] += v;
        __syncthreads();
    }
    if (i < N) start[i] = sdata[threadIdx.x] - orig + partial[blockIdx.x];
}

// ---------------- place edges into CSR ----------------
__global__ void k_place(const int* __restrict__ row, const int* __restrict__ col,
                        const int* __restrict__ start, int* __restrict__ cursor,
                        int* __restrict__ adj, int E) {
    int e = blockIdx.x * blockDim.x + threadIdx.x;
    if (e < E) {
        int c = col[e];
        int p = atomicAdd(&cursor[c], 1);
        adj[start[c] + p] = row[e];
    }
}

// ---------------- GEMM [N,64]@[64,64], epilogue *dinv[row] ----------------
__global__ __launch_bounds__(256) void k_gemm64(const float* __restrict__ H,
                                                const float* __restrict__ W,
                                                const float* __restrict__ dinv,
                                                float* __restrict__ O, int N) {
    __shared__ float Ws[64 * 64];
    __shared__ float Hs[16 * 64];
    int tid = threadIdx.x;
    #pragma unroll
    for (int i = tid; i < 64 * 64; i += 256) Ws[i] = W[i];
    int rbase = blockIdx.x * 16;
    #pragma unroll
    for (int i = tid; i < 16 * 64; i += 256) {
        int r = rbase + (i >> 6);
        Hs[i] = (r < N) ? H[(size_t)r * HID + (i & 63)] : 0.0f;
    }
    __syncthreads();
    int c = tid & 63;
    int lr = (tid >> 6) * 4;           // local row 0,4,8,12
    float a0 = 0, a1 = 0, a2 = 0, a3 = 0;
    const float* h = Hs + lr * 64;
    #pragma unroll
    for (int k = 0; k < 64; ++k) {
        float w = Ws[k * 64 + c];
        a0 += h[k] * w;
        a1 += h[64 + k] * w;
        a2 += h[128 + k] * w;
        a3 += h[192 + k] * w;
    }
    int r = rbase + lr;
    if (r + 3 < N) {
        float* o = O + (size_t)r * HID;
        o[c]       = a0 * dinv[r];
        o[64 + c]  = a1 * dinv[r + 1];
        o[128 + c] = a2 * dinv[r + 2];
        o[192 + c] = a3 * dinv[r + 3];
    } else {
        if (r < N)     O[(size_t)r * HID + c]       = a0 * dinv[r];
        if (r + 1 < N) O[(size_t)(r + 1) * HID + c] = a1 * dinv[r + 1];
        if (r + 2 < N) O[(size_t)(r + 2) * HID + c] = a2 * dinv[r + 2];
        if (r + 3 < N) O[(size_t)(r + 3) * HID + c] = a3 * dinv[r + 3];
    }
}

// ---------------- gather-aggregate per node (one wave per node) ----------------
// out[c] = act( dinv[c] * (xws[c] + sum_{e into c} xws[adj[e]]) + b )
__global__ __launch_bounds__(256) void k_gather(const int* __restrict__ adj,
                                                const int* __restrict__ start,
                                                const int* __restrict__ cnt,
                                                const float* __restrict__ dinv,
                                                const float* __restrict__ xws,
                                                const float* __restrict__ b,
                                                float* __restrict__ out,
                                                int N, int do_relu) {
    int node = blockIdx.x * 4 + (threadIdx.x >> 6);
    int f = threadIdx.x & 63;
    if (node >= N) return;
    int s = start[node];
    int n = cnt[node];
    float acc = xws[(size_t)node * HID + f];      // self loop
    int i = 0;
    for (; i + 4 <= n; i += 4) {
        int r0 = adj[s + i], r1 = adj[s + i + 1], r2 = adj[s + i + 2], r3 = adj[s + i + 3];
        float v0 = xws[(size_t)r0 * HID + f];
        float v1 = xws[(size_t)r1 * HID + f];
        float v2 = xws[(size_t)r2 * HID + f];
        float v3 = xws[(size_t)r3 * HID + f];
        acc += v0 + v1 + v2 + v3;
    }
    for (; i < n; ++i) acc += xws[(size_t)adj[s + i] * HID + f];
    float v = acc * dinv[node] + b[f];
    out[(size_t)node * HID + f] = do_relu ? fmaxf(v, 0.0f) : v;
}

// ---------------- batch histogram (graph sizes) ----------------
__global__ void k_bhist(const int* __restrict__ batch, int N, int* __restrict__ bcnt) {
    int i = blockIdx.x * blockDim.x + threadIdx.x;
    if (i < N) atomicAdd(&bcnt[batch[i]], 1);
}

// single-block exclusive scan over 500 graph counts
__global__ void k_bscan(const int* __restrict__ bcnt, int* __restrict__ bstart) {
    __shared__ int s[512];
    int t = threadIdx.x;
    int v = (t < N_GRAPHS) ? bcnt[t] : 0;
    s[t] = v;
    __syncthreads();
    for (int off = 1; off < 512; off <<= 1) {
        int u = (t >= off) ? s[t - off] : 0;
        __syncthreads();
        s[t] += u;
        __syncthreads();
    }
    if (t < N_GRAPHS) bstart[t] = s[t] - v;   // exclusive
}

// ---------------- segmented mean pool: one block per graph, no atomics ----------------
__global__ __launch_bounds__(256) void k_pmean(const float* __restrict__ h,
                                               const int* __restrict__ bstart,
                                               const int* __restrict__ bcnt,
                                               float* __restrict__ mean) {
    int g = blockIdx.x;
    int s = bstart[g], n = bcnt[g];
    int f = threadIdx.x & 63, w = threadIdx.x >> 6;
    float acc = 0.0f;
    for (int i = s + w; i < s + n; i += 4) acc += h[(size_t)i * HID + f];
    __shared__ float lds[256];
    lds[threadIdx.x] = acc;
    __syncthreads();
    if (w == 0) {
        float tot = lds[f] + lds[64 + f] + lds[128 + f] + lds[192 + f];
        mean[(size_t)g * HID + f] = tot / fmaxf((float)n, 1.0f);
    }
}

// ---------------- final linear: out[g,c] = mean[g] @ Wl + bl ----------------
__global__ void k_final(const float* __restrict__ mean,
                        const float* __restrict__ Wl, const float* __restrict__ bl,
                        float* __restrict__ out) {
    int gid = blockIdx.x * blockDim.x + threadIdx.x;
    if (gid >= N_GRAPHS * N_CLS) return;
    int g = gid >> 3, c = gid & 7;
    float acc = bl[c];
    #pragma unroll
    for (int f = 0; f < HID; ++f) acc += mean[(size_t)g * HID + f] * Wl[f * N_CLS + c];
    out[gid] = acc;
}

extern "C" void kernel_launch(void* const* d_in, const int* in_sizes, int n_in,
                              void* d_out, int out_size, void* d_ws, size_t ws_size,
                              hipStream_t stream) {
    const float* x     = (const float*)d_in[0];
    const int*   ei    = (const int*)d_in[1];
    const int*   batch = (const int*)d_in[2];
    const float* W1    = (const float*)d_in[3];
    const float* b1    = (const float*)d_in[4];
    const float* W2    = (const float*)d_in[5];
    const float* b2    = (const float*)d_in[6];
    const float* W3    = (const float*)d_in[7];
    const float* b3    = (const float*)d_in[8];
    const float* Wl    = (const float*)d_in[9];
    const float* bl    = (const float*)d_in[10];
    float* out = (float*)d_out;

    const int N = in_sizes[0] / HID;   // 50000
    const int E = in_sizes[1] / 2;     // 800000
    const int* row = ei;
    const int* col = ei + E;

    // ---- workspace layout (4-byte units) ----
    char* wsb = (char*)d_ws;
    int*   cnt     = (int*)wsb;                         // N
    int*   start   = cnt + 50048;                       // N
    int*   cursor  = start + 50048;                     // N
    int*   partial = cursor + 50048;                    // 256
    float* dinv    = (float*)(partial + 256);           // N
    int*   bcnt    = (int*)(dinv + 50048);              // 512
    int*   bstart  = bcnt + 512;                        // 512
    float* mean    = (float*)(bstart + 512);            // 500*64
    int*   adj     = (int*)(mean + 32000);              // E
    float* bufA    = (float*)(adj + 800000);            // N*64
    float* bufB    = bufA + (size_t)N * HID;            // N*64

    const int T = 256;
    const int nblk = (N + 255) / 256;                   // 196

    // zero: cnt, cursor, batch histogram
    hipMemsetAsync(cnt, 0, (size_t)N * sizeof(int), stream);
    hipMemsetAsync(cursor, 0, (size_t)N * sizeof(int), stream);
    hipMemsetAsync(bcnt, 0, 512 * sizeof(int), stream);

    // ---- CSR build + dinv + graph ranges ----
    k_hist <<<(E + T - 1) / T, T, 0, stream>>>(col, E, cnt);
    k_dinv <<<nblk, T, 0, stream>>>(cnt, dinv, N);
    k_scan1<<<nblk, T, 0, stream>>>(cnt, partial, N);
    k_scan2<<<1, T, 0, stream>>>(partial, nblk);
    k_scan3<<<nblk, T, 0, stream>>>(cnt, partial, start, N);
    k_place<<<(E + T - 1) / T, T, 0, stream>>>(row, col, start, cursor, adj, E);
    k_bhist<<<nblk, T, 0, stream>>>(batch, N, bcnt);
    k_bscan<<<1, 512, 0, stream>>>(bcnt, bstart);

    int gGemm = (N + 15) / 16;          // 3125
    int gGath = (N + 3) / 4;            // 12500

    // ---- layer 1 ----
    k_gemm64<<<gGemm, T, 0, stream>>>(x, W1, dinv, bufA, N);
    k_gather<<<gGath, T, 0, stream>>>(adj, start, cnt, dinv, bufA, b1, bufB, N, 1);
    // ---- layer 2 ----
    k_gemm64<<<gGemm, T, 0, stream>>>(bufB, W2, dinv, bufA, N);
    k_gather<<<gGath, T, 0, stream>>>(adj, start, cnt, dinv, bufA, b2, bufB, N, 1);
    // ---- layer 3 ----
    k_gemm64<<<gGemm, T, 0, stream>>>(bufB, W3, dinv, bufA, N);
    k_gather<<<gGath, T, 0, stream>>>(adj, start, cnt, dinv, bufA, b3, bufB, N, 0);

    // ---- pool + head (segmented, no atomics) ----
    k_pmean<<<N_GRAPHS, T, 0, stream>>>(bufB, bstart, bcnt, mean);
    k_final<<<(N_GRAPHS * N_CLS + T - 1) / T, T, 0, stream>>>(mean, Wl, bl, out);
}